// Round 10
// baseline (170.101 us; speedup 1.0000x reference)
//
#include <hip/hip_runtime.h>

// RelatEntAtt: E=4096, R=64, D=256. Fully fused recompute; att (E,R,D) never
// materialized. exp2 with log2(e) folded into the adj-softmax output.
// R2 (180.9us): CH=8, JT=16, arrays SROA to regs. Grid 512 -> 18% occ.
// R3/R4 (FAILED): CH=4 breaks SROA (~470 MB scratch traffic). CH=8 + JT=16
//     private-array shapes are load-bearing. DO NOT TOUCH.
// R5 (181us): j-half split, grid 1024. kB 73->65us. SROA held.
// R6 (170us) / R11 (167.1us, PASSED, BEST): j-quarter split, grid 2048.
//     kB 58.5us, VALUBusy 67%, FETCH 17.6MB, occ 33%.
// R7 (FAILED): hipLaunchCooperativeKernel incompatible with harness capture.
// R8 (FAILED): spin grid-barrier -> likely deadlock. NO SPINS.
// R9 (FAILED for other reasons): last-arriver tails read partially-accumulated
//     remote-XCD atomics -> atomic results only consumable across a kernel
//     boundary. BUT: its adj-softmax-fused-into-kA/kB prologue ran correctly
//     (hout passed) -> that fold is validated.
// R10 (FAILED): bisection multi-reduce raised live regs ~+30 -> spill. The
//     row16_sum immediate-consume DPP scan is register-minimal, load-bearing.
// R12: k_adj eliminated. adj-softmax folded into kA/kB prologues (identical
//     fp32 sequence in both -> bit-identical s2 values; s2 buffer deleted).
//     Zeroing via plain hipMemsetAsync (8.25 MB). Sweep bodies R11-VERBATIM.

#define EN 4096
#define RN 64
#define DN 256
#define JT 16          // j-tile width (PROVEN SROA shape - do not change)
#define LOG2E 1.44269504088896340736f
#define CHA 8   // e's per block in kA (PROVEN SROA shape - do not change)
#define CHB 8   // e's per block in kB (PROVEN SROA shape - do not change)
#define GRIDAB ((EN/CHA)*4)            // 2048 blocks: (e-chunk, j-quarter)

__device__ __forceinline__ float ex2(float x){ return __builtin_amdgcn_exp2f(x); }
__device__ __forceinline__ float rcpf(float x){ return __builtin_amdgcn_rcpf(x); }

template<int CTRL>
__device__ __forceinline__ float dpp_add(float v){
  int m = __builtin_amdgcn_update_dpp(0, __float_as_int(v), CTRL, 0xf, 0xf, true);
  return v + __int_as_float(m);
}
// lane (i%16)==15 ends with the sum of its 16-lane row
__device__ __forceinline__ float row16_sum(float v){
  v = dpp_add<0x111>(v);
  v = dpp_add<0x112>(v);
  v = dpp_add<0x114>(v);
  v = dpp_add<0x118>(v);
  return v;
}

// in-block adj softmax for rows e0..e0+7, keeping quarter [j0, j0+16) in s2s.
// IDENTICAL fp32 instruction sequence in kA and kB -> bit-identical values ->
// consistent normalization across both sweeps (validated by R9's passing hout).
// wave w handles rows w and w+4; lane = j over the full 64-j row.
__device__ __forceinline__ void adj_quarter(const float* __restrict__ adj,
                                            int e0, int j0, int tid,
                                            float* __restrict__ s2s){
  const int w = tid >> 6, lane = tid & 63;
  #pragma unroll
  for(int rr2 = 0; rr2 < 2; rr2++){
    const int row = rr2*4 + w;
    float a  = adj[(e0 + row)*RN + lane];
    float ev = ex2(a * LOG2E);
    float s  = ev;
    #pragma unroll
    for(int off = 32; off > 0; off >>= 1) s += __shfl_xor(s, off, 64);
    float val = ev * (LOG2E * rcpf(s));
    const unsigned lj = (unsigned)(lane - j0);
    if(lj < 16u) s2s[row*JT + (int)lj] = val;
  }
  __syncthreads();
}

// ---- kA: lRg[e,d] += sum_(own j) ev;  lE[j,d] += ev ----
// block = (e-chunk, j-quarter): e0 = (bid>>2)*CHA, j0 = (bid&3)*16
__global__ __launch_bounds__(256,4) void kA(const float* __restrict__ h,
                                            const float* __restrict__ r,
                                            const float* __restrict__ adj,
                                            float* __restrict__ lRg,
                                            float* __restrict__ lE){
  const int d  = threadIdx.x;
  const int e0 = (blockIdx.x >> 2) * CHA;
  const int j0 = (blockIdx.x & 3) * JT;
  __shared__ float s2s[CHA*JT];            // 512 B
  adj_quarter(adj, e0, j0, d, s2s);

  float lR[CHA];
  #pragma unroll
  for(int ee = 0; ee < CHA; ee++) lR[ee] = 0.f;

  float rcol[JT], lEacc[JT];
  #pragma unroll
  for(int jj = 0; jj < JT; jj++){ rcol[jj] = r[(j0+jj)*DN + d]; lEacc[jj] = 0.f; }
  #pragma unroll
  for(int ee = 0; ee < CHA; ee++){
    const float he = h[(e0+ee)*DN + d];
    #pragma unroll
    for(int jj = 0; jj < JT; jj++){
      float t  = s2s[ee*JT + jj] * he * rcol[jj];
      float ev = ex2(fmaxf(t, 0.2f*t));
      lR[ee]   += ev;
      lEacc[jj] += ev;
    }
  }
  #pragma unroll
  for(int jj = 0; jj < JT; jj++) atomicAdd(&lE[(j0+jj)*DN + d], lEacc[jj]);
  #pragma unroll
  for(int ee = 0; ee < CHA; ee++) atomicAdd(&lRg[(e0+ee)*DN + d], lR[ee]);
}

// ---- kB: main fused sweep over own j-quarter ----
// per (e,d): pR = ev/lRg (att_R), pE = ev/lE (att_E)
//   sEg[e,d] += sum_(own j) pE      (atomics; h' ELU in kTail)
//   r'[j,d] += pR                   16-reg acc, atomic flush
//   alog[e,j] = sum_d pR*W_d        row16 DPP + LDS partial combine (j owned)
__global__ __launch_bounds__(256,4) void kB(const float* __restrict__ h,
                                            const float* __restrict__ r,
                                            const float* __restrict__ adj,
                                            const float* __restrict__ lRg,
                                            const float* __restrict__ lE,
                                            const float* __restrict__ W,
                                            float* __restrict__ alog,
                                            float* __restrict__ racc_g,
                                            float* __restrict__ sEg){
  const int tid  = threadIdx.x;            // = d
  const int lane = tid & 63;
  const int grp  = tid >> 4;               // 16 groups of 16 lanes
  const int e0   = (blockIdx.x >> 2) * CHB;
  const int j0   = (blockIdx.x & 3) * JT;
  __shared__ float s2s[CHB*JT];            // 512 B
  __shared__ float apart[CHB*16*20];       // [ee][g][jj], jj stride 1, g stride 20 -> 10 KB
  adj_quarter(adj, e0, j0, tid, s2s);

  const float wd = W[tid];
  float sE[CHB];
  #pragma unroll
  for(int ee = 0; ee < CHB; ee++) sE[ee] = 0.f;

  float rcol[JT], ile[JT], rAcc[JT];
  #pragma unroll
  for(int jj = 0; jj < JT; jj++){
    const int j = j0 + jj;
    rcol[jj] = r[j*DN + tid];
    ile[jj]  = rcpf(lE[j*DN + tid]);
    rAcc[jj] = 0.f;
  }
  for(int ee = 0; ee < CHB; ee++){
    const int e = e0 + ee;
    const float he = h[e*DN + tid];
    const float il = rcpf(lRg[e*DN + tid]);
    const float u  = il * wd;
    #pragma unroll
    for(int jg = 0; jg < JT/4; jg++){
      float4 st;
      #pragma unroll
      for(int jj4 = 0; jj4 < 4; jj4++){
        const int jj = jg*4 + jj4;
        float t  = s2s[ee*JT + jj] * he * rcol[jj];
        float ev = ex2(fmaxf(t, 0.2f*t));
        rAcc[jj] = fmaf(ev, il, rAcc[jj]);      // pR accumulated over e
        sE[ee]   = fmaf(ev, ile[jj], sE[ee]);   // pE sum over own j
        float rs = row16_sum(ev * u);           // alog contribution
        if(jj4==0) st.x = rs; else if(jj4==1) st.y = rs;
        else if(jj4==2) st.z = rs; else st.w = rs;
      }
      if((lane & 15) == 15){
        *reinterpret_cast<float4*>(&apart[(ee*16 + grp)*20 + jg*4]) = st;
      }
    }
  }
  __syncthreads();
  if(tid < CHB*JT){                        // 128 threads: ee = tid>>4, jj = tid&15
    const int ee = tid >> 4, jj = tid & 15;
    float sum = 0.f;
    #pragma unroll
    for(int g = 0; g < 16; g++) sum += apart[(ee*16 + g)*20 + jj];
    alog[(e0+ee)*RN + j0 + jj] = sum;
  }
  #pragma unroll
  for(int jj = 0; jj < JT; jj++) atomicAdd(&racc_g[(j0+jj)*DN + tid], rAcc[jj]);
  #pragma unroll
  for(int ee = 0; ee < CHB; ee++) atomicAdd(&sEg[(e0+ee)*DN + tid], sE[ee]);
}

// ---- tail: hout = elu(h*sEg) everywhere; blocks 0..63 also do rout + alpha ----
// (reference's reshape(R,E,1)+softmax(axis=1) == per-row softmax on the e*64+j
//  flat array viewed as [64][4096]; b_lin dropped by shift invariance)
__global__ __launch_bounds__(256) void kTail(const float* __restrict__ h,
                                             const float* __restrict__ sEg,
                                             const float* __restrict__ alog,
                                             const float* __restrict__ r,
                                             const float* __restrict__ racc,
                                             float* __restrict__ hout,
                                             float* __restrict__ rout,
                                             float* __restrict__ aout){
  const int b = blockIdx.x, tid = threadIdx.x;
  {
    const int i = b*256 + tid;               // grid 4096 covers EN*DN
    float hp = h[i] * sEg[i];
    hout[i] = hp > 0.f ? hp : (ex2(hp*LOG2E) - 1.0f);
  }
  if(b < RN){                                 // block-uniform branch
    const int i = b*DN + tid;
    float v = r[i] * racc[i];
    rout[i] = v > 0.f ? v : (ex2(v*LOG2E) - 1.0f);

    const float* __restrict__ row = alog + b*EN;
    float exv[16]; float s = 0.f;
    #pragma unroll
    for(int k = 0; k < 16; k++){
      float v2 = ex2(row[k*256 + tid] * LOG2E);
      exv[k] = v2; s += v2;
    }
    #pragma unroll
    for(int off = 32; off > 0; off >>= 1) s += __shfl_xor(s, off, 64);
    __shared__ float wsum[4];
    if((tid & 63) == 0) wsum[tid>>6] = s;
    __syncthreads();
    float inv = 1.0f / (wsum[0] + wsum[1] + wsum[2] + wsum[3]);
    float* __restrict__ orow = aout + b*EN;
    #pragma unroll
    for(int k = 0; k < 16; k++) orow[k*256 + tid] = exv[k] * inv;
  }
}

extern "C" void kernel_launch(void* const* d_in, const int* in_sizes, int n_in,
                              void* d_out, int out_size, void* d_ws, size_t ws_size,
                              hipStream_t stream){
  (void)in_sizes; (void)n_in; (void)out_size; (void)ws_size;
  const float* h   = (const float*)d_in[0];
  const float* r   = (const float*)d_in[1];
  const float* adj = (const float*)d_in[2];
  const float* W   = (const float*)d_in[3];
  // d_in[4] = b_lin: unused (softmax shift invariance)

  float* ws   = (float*)d_ws;
  float* lE   = ws;                  // RN*DN  --+
  float* racc = lE + RN*DN;          // RN*DN    | one contiguous memset
  float* lRg  = racc + RN*DN;        // EN*DN    |
  float* sEg  = lRg + EN*DN;         // EN*DN  --+
  float* alog = sEg + EN*DN;         // EN*RN

  float* hout = (float*)d_out;           // EN*DN
  float* rout = hout + EN*DN;            // RN*DN
  float* aout = rout + RN*DN;            // RN*EN

  hipMemsetAsync(lE, 0, size_t(RN*DN*2 + EN*DN*2)*sizeof(float), stream);
  kA   <<<GRIDAB,    256, 0, stream>>>(h, r, adj, lRg, lE);
  kB   <<<GRIDAB,    256, 0, stream>>>(h, r, adj, lRg, lE, W, alog, racc, sEg);
  kTail<<<EN*DN/256, 256, 0, stream>>>(h, sEg, alog, r, racc, hout, rout, aout);
}